// Round 7
// baseline (237.466 us; speedup 1.0000x reference)
//
#include <hip/hip_runtime.h>
#include <hip/hip_bf16.h>

// Loss = L1*sl1(1,iou) + L2*sl1(t[:4],p[:4]) + L3*sl1(t[12],p[12]) + 0.5*L4*sl1(t[4:12],p[4:12])
// shapes: (B=256, N=8192, F=13) fp32. B*N = 2^21 rows.
//
// R7: "superblock" register kernel. 52 floats = 208 B = exactly 4 rows.
// 2048 blocks x 256 threads = 524,288 threads = one superblock per thread
// (2^21 rows total, exact). Each thread: 13 float4 loads from T + 13 from P
// (single base pointer, constexpr offsets -> immediate-offset dwordx4 loads),
// then FULLY UNROLLED arithmetic: every feature index, row index and weight
// is a compile-time constant; the v[52] arrays fold into registers. IoU for
// the 4 rows comes straight from registers. No LDS staging, no barriers in
// the hot path, no runtime mod-13, nothing to spill by construction.
// launch_bounds(256,2) -> ~200 VGPR budget for deep load hoisting (MLP).

#define NBLK 2048
#define TPB  256

// Exact power-of-two mean weights (B*N = 2^21):
#define W1 (1.0f / 2097152.0f)    // loss1: 1/(B*N)
#define W2 (1.0f / 8388608.0f)    // loss2: 1/(B*N*4)
#define W3 (1.0f / 2097152.0f)    // loss3: 1/(B*N)
#define W4 (1.0f / 33554432.0f)   // loss4: 0.5/(B*N*8)

__device__ __forceinline__ float sl1(float d) {
    d = fabsf(d);
    return d < 1.0f ? 0.5f * d * d : d - 0.5f;
}

__global__ __launch_bounds__(TPB, 2) void loss_stage1(const float* __restrict__ T,
                                                      const float* __restrict__ P,
                                                      float* __restrict__ partial) {
    __shared__ float wred[4];

    const int tid  = threadIdx.x;
    const long long sb = (long long)blockIdx.x * TPB + tid;   // superblock id

    const float4* __restrict__ t4 = (const float4*)(T + sb * 52);
    const float4* __restrict__ p4 = (const float4*)(P + sb * 52);

    // 26 independent loads, constexpr offsets — compiler hoists the whole run.
    float4 tv4[13], pv4[13];
#pragma unroll
    for (int k = 0; k < 13; ++k) tv4[k] = t4[k];
#pragma unroll
    for (int k = 0; k < 13; ++k) pv4[k] = p4[k];

    // Reinterpret as flat 52-float register arrays (all indices constexpr).
    const float* tv = (const float*)tv4;
    const float* pv = (const float*)pv4;

    float acc = 0.0f;

    // ---- elementwise terms: weight by feature = idx % 13, compile-time ----
#pragma unroll
    for (int e = 0; e < 52; ++e) {
        constexpr_weight:;
        const int f = e % 13;                       // compile-time per iteration
        const float w = (f < 4) ? W2 : ((f == 12) ? W3 : W4);
        acc += w * sl1(tv[e] - pv[e]);
    }

    // ---- IoU for the 4 rows, straight from registers ----
#pragma unroll
    for (int r = 0; r < 4; ++r) {
        const int b = r * 13;                       // compile-time
        float t0 = tv[b+0], t1 = tv[b+1], t2 = tv[b+2], t3 = tv[b+3];
        float p0 = pv[b+0], p1 = pv[b+1], p2 = pv[b+2], p3 = pv[b+3];

        float w = fmaxf(fminf(t2, p2) - fmaxf(t0, p0), 0.0f);
        float h = fmaxf(fminf(t3, p3) - fmaxf(t1, p1), 0.0f);
        float inter = w * h;
        float a1 = (t2 - t0) * (t3 - t1);
        float a2 = (p2 - p0) * (p3 - p1);
        float iou = inter / (a1 + a2 - inter + 1e-7f);
        acc += W1 * sl1(1.0f - iou);
    }

    // ---- block reduction: wave64 shuffle -> 4-wave LDS -> one partial ----
#pragma unroll
    for (int off = 32; off > 0; off >>= 1)
        acc += __shfl_down(acc, off, 64);
    if ((tid & 63) == 0) wred[tid >> 6] = acc;
    __syncthreads();
    if (tid == 0)
        partial[blockIdx.x] = wred[0] + wred[1] + wred[2] + wred[3];
}

__global__ __launch_bounds__(256) void loss_stage2(const float* __restrict__ partial,
                                                   float* __restrict__ out) {
    __shared__ float wred[4];
    const int tid = threadIdx.x;
    float a = 0.0f;
#pragma unroll
    for (int k = 0; k < NBLK / 256; ++k) a += partial[k * 256 + tid];
#pragma unroll
    for (int off = 32; off > 0; off >>= 1)
        a += __shfl_down(a, off, 64);
    if ((tid & 63) == 0) wred[tid >> 6] = a;
    __syncthreads();
    if (tid == 0) out[0] = wred[0] + wred[1] + wred[2] + wred[3];
}

extern "C" void kernel_launch(void* const* d_in, const int* in_sizes, int n_in,
                              void* d_out, int out_size, void* d_ws, size_t ws_size,
                              hipStream_t stream) {
    const float* targets = (const float*)d_in[0];
    const float* preds   = (const float*)d_in[1];
    float* out     = (float*)d_out;
    float* partial = (float*)d_ws;   // NBLK floats = 8 KB scratch

    loss_stage1<<<NBLK, TPB, 0, stream>>>(targets, preds, partial);
    loss_stage2<<<1, 256, 0, stream>>>(partial, out);
}